// Round 12
// baseline (9389.372 us; speedup 1.0000x reference)
//
#include <hip/hip_runtime.h>

#define Bsz 256
#define Tt  512
#define Hh  128

// ws layout (floats):
//   Wblob [3][8 waves][64 j][64 lane][4]  per-thread repacked weights (393216 floats)
//       float4 index = l*32768 + w*4096 + j*64 + lane ; j<32 = ih-half, j>=32 = hh-half
//   bias  [3][512]            bih + bhh                      @ OFF_BIAS
//   hbuf  u64[4][3][256][128] 4-deep hidden states, (seq<<32)|bits(h), sc1 path
//   flags [2][64] x 32        staged-progress of consumer blocks (layers 1,2), 128B apart
#define OFF_BIAS 393216
#define OFF_HBUF 394752            // u64 array = 786432 floats
#define OFF_FLAG 1181184
#define FLAG_N   4096              // 128 flags * 32 ints
// total used: 1185280 floats = 4.74 MB

// swizzled LDS column: k -> (k>>3)*12 + (k&7); 8-float groups at 48B stride
// -> 16 wave-distinct addrs, 2-way max bank aliasing (free), 16B-aligned b128 reads.
#define SKG(k) ((((k) >> 3) * 12) + ((k) & 7))

typedef unsigned long long u64;
typedef unsigned int u32;

// ---- MALL-coherent (sc0 sc1 per-access) relaxed agent-scope atomics ----
__device__ __forceinline__ void st_h_agent(u64* p, float v, u32 seq) {
    u64 u = ((u64)seq << 32) | (u64)__float_as_uint(v);
    __hip_atomic_store(p, u, __ATOMIC_RELAXED, __HIP_MEMORY_SCOPE_AGENT);
}
__device__ __forceinline__ u64 ld_u64_agent(const u64* p) {
    return __hip_atomic_load(p, __ATOMIC_RELAXED, __HIP_MEMORY_SCOPE_AGENT);
}

// fast tanh: 1 - 2/(e^{2x}+1); saturates correctly (verified r11, absmax 1.9e-6).
__device__ __forceinline__ float fast_tanh(float x) {
    float e = __expf(2.f * x);
    return 1.f - 2.f / (e + 1.f);
}

// compile-time float4 component pick (indices constant after unroll -> no scratch)
__device__ __forceinline__ float f4c(const float4& v, int i) {
    switch (i & 3) { case 0: return v.x; case 1: return v.y; case 2: return v.z; default: return v.w; }
}

// VALU-pipe partial-row reduction: lane 15 of each 16-lane DPP row ends with the
// sum of lanes 0..15. bound_ctrl=1 -> 0-fill. (verified r4-r11)
template<int N>
__device__ __forceinline__ float row_shr_add(float v) {
    int s = __builtin_amdgcn_update_dpp(0, __float_as_int(v), 0x110 + N, 0xF, 0xF, true);
    return v + __int_as_float(s);
}
__device__ __forceinline__ float4 red16(float4 s) {
    s.x = row_shr_add<1>(s.x); s.x = row_shr_add<2>(s.x); s.x = row_shr_add<4>(s.x); s.x = row_shr_add<8>(s.x);
    s.y = row_shr_add<1>(s.y); s.y = row_shr_add<2>(s.y); s.y = row_shr_add<4>(s.y); s.y = row_shr_add<8>(s.y);
    s.z = row_shr_add<1>(s.z); s.z = row_shr_add<2>(s.z); s.z = row_shr_add<4>(s.z); s.z = row_shr_add<8>(s.z);
    s.w = row_shr_add<1>(s.w); s.w = row_shr_add<2>(s.w); s.w = row_shr_add<4>(s.w); s.w = row_shr_add<8>(s.w);
    return s;
}

#define FMA4(S, A, W) { S.x = fmaf(A, W.x, S.x); S.y = fmaf(A, W.y, S.y); \
                        S.z = fmaf(A, W.z, S.z); S.w = fmaf(A, W.w, S.w); }

// prep: repack weights into per-thread lane-contiguous blobs + bias + inits.
// One float4 of the blob per gid (98304 total = 384 blocks x 256 threads).
__global__ void prep_kernel(const float* Wih0, const float* Whh0, const float* bih0, const float* bhh0,
                            const float* Wih1, const float* Whh1, const float* bih1, const float* bhh1,
                            const float* Wih2, const float* Whh2, const float* bih2, const float* bhh2,
                            float* ws)
{
    int gid = blockIdx.x * blockDim.x + threadIdx.x;   // 0..98303
    if (gid < FLAG_N) ((int*)(ws + OFF_FLAG))[gid] = -1;
    u64* hb = (u64*)(ws + OFF_HBUF);                   // seq init: never matches
    for (int i = gid; i < 4 * 3 * 256 * 128; i += 98304) hb[i] = 0xFFFFFFFF00000000ull;

    if (gid < 1536) {   // bias
        int l = gid >> 9, gc = gid & 511;
        const float* bih = (l == 0) ? bih0 : (l == 1) ? bih1 : bih2;
        const float* bhh = (l == 0) ? bhh0 : (l == 1) ? bhh1 : bhh2;
        ws[OFF_BIAS + l * 512 + gc] = bih[gc] + bhh[gc];
    }

    // weight blob float4 #gid = (l, w, j, lane)
    int l    = gid >> 15;              // 32768 float4 per layer
    int r1   = gid & 32767;
    int w    = r1 >> 12;               // 4096 float4 per wave-blob
    int r2   = r1 & 4095;
    int j    = r2 >> 6;                // 64 dwordx4 per thread
    int lane = r2 & 63;
    int tid  = w * 64 + lane;
    int kg   = tid & 15, og = tid >> 4;
    const float* Wih = (l == 0) ? Wih0 : (l == 1) ? Wih1 : Wih2;
    const float* Whh = (l == 0) ? Whh0 : (l == 1) ? Whh1 : Whh2;
    int Kin = (l == 0) ? 8 : 128;
    float v[4];
    for (int qq = 0; qq < 4; qq++) {
        int jj = (j < 32) ? j : j - 32;
        int q = jj * 4 + qq;             // q>>4 = kk (k-sub), q&15 = cc (col offset)
        int k = kg * 8 + (q >> 4);
        int c = og * 16 + (q & 15);
        v[qq] = (j < 32) ? ((k < Kin) ? Wih[c * Kin + k] : 0.f)
                         : Whh[c * 128 + k];
    }
    ((float4*)ws)[gid] = make_float4(v[0], v[1], v[2], v[3]);
}

// Persistent kernel, 192 blocks x 512 threads (1 block/CU region, 2 waves/SIMD).
// block = (layer, rtile): 4 batch rows x ALL 128 hidden cols -> the RECURRENCE IS
// BLOCK-LOCAL (h round-trips through LDS, not MALL). Cross-block edge is only the
// 1:1 layer->layer handoff (seq-tagged u64, 1 value/thread, early-issued and
// hidden under the rec-half GEMM; 1 slot of inherent slack). Weights stream from
// L2 each slot via perfectly-coalesced per-thread blobs (512 KB/block/slot; all
// 3 layers L2-resident per XCD). Thread (kg=tid&15, og=tid>>4): 4 rows x 16 cols,
// k-slice kg*8..+8 of both halves; DPP reduce over 16 kg lanes (verified tree).
__global__ __launch_bounds__(512, 2) void lstm_kernel(const float* __restrict__ x,
                                                      float* __restrict__ ws)
{
    const float* __restrict__ bias = ws + OFF_BIAS;
    u64* __restrict__ hbuf = (u64*)(ws + OFF_HBUF);
    int* __restrict__ fl = (int*)(ws + OFF_FLAG);

    const int layer = blockIdx.x >> 6;     // 0..2
    const int rt    = blockIdx.x & 63;     // 0..63
    const int r0    = rt << 2;             // batch rows [r0, r0+4)
    const int tid   = threadIdx.x;

    __shared__ float sAin[4][192];         // staged input (x or lower-layer h), SKG layout
    __shared__ float hrec[4][192];         // block-local recurrent h, SKG layout
    __shared__ float sG[4][516];           // gates, raw gate-col index 0..511

    for (int i = tid; i < 4 * 192; i += 512) ((float*)sAin)[i] = 0.f;  // layer0 k>=8 zeros

    const int kg   = tid & 15;             // k-group (DPP-row lane 0..15)
    const int og   = tid >> 4;             // output col-group 0..31 (cols og*16..+15)
    const int w    = tid >> 6;             // wave 0..7
    const int lane = tid & 63;

    // per-thread weight blob: wq[j*64] = j-th dwordx4 (j<32 ih, j>=32 hh)
    const float4* __restrict__ wq =
        (const float4*)ws + ((size_t)layer << 15) + ((size_t)w << 12) + lane;

    float4 bias4[4];
#pragma unroll
    for (int cq = 0; cq < 4; cq++)
        bias4[cq] = (kg == 15) ? *(const float4*)&bias[layer * 512 + og * 16 + cq * 4]
                               : make_float4(0.f, 0.f, 0.f, 0.f);

    // staging: 1 u64 per thread (rows 4 x 128 cols = 512 values)
    const int sr = tid >> 7, shc = tid & 127;
    const int s_lds = SKG(shc);

    // cell: 1 cell per thread
    const int ur = tid >> 7, uc = tid & 127;
    const int u_lds = SKG(uc);
    float creg = 0.f;

    // flags: flag[(l-1)*64+rt] = staged-progress of block (l, rt), l in {1,2}
    int* myflag  = (layer >= 1) ? fl + ((layer - 1) * 64 + rt) * 32 : nullptr;
    int* depflag = (layer <= 1) ? fl + (layer * 64 + rt) * 32 : nullptr;  // consumer (layer+1)

    __syncthreads();   // sAin zero-fill visible

    for (int t = 0; t < Tt; ++t) {
        const int s = t + layer;
        const int prev = (s - 1) & 3, cur = s & 3;   // depth-4 buffering
        const u32 expseq = (u32)(s - 1);

        // ---- early input load (1 u64/thread); completes under rec-half GEMM ----
        u64 hv = 0; float xv = 0.f;
        const u64* src = nullptr;
        if (layer > 0) {
            src = hbuf + ((size_t)prev * 3 + (layer - 1)) * Bsz * Hh
                + (size_t)(r0 + sr) * Hh + shc;
            hv = ld_u64_agent(src);
        } else if (tid < 32) {
            int r = tid >> 3, i = tid & 7;
            xv = x[((size_t)(r0 + r) * Tt + t) * 8 + i];
        }

        // ---- accumulators (bias preloaded at reduction root) ----
        float4 acc[16];
#pragma unroll
        for (int r = 0; r < 4; r++)
#pragma unroll
            for (int cq = 0; cq < 4; cq++) acc[r * 4 + cq] = bias4[cq];

        // ---- rec-half: BLOCK-LOCAL h from LDS (skip t=0: h0 = 0) ----
        if (t > 0) {
            float4 aR[4][2];
#pragma unroll
            for (int r = 0; r < 4; r++) {
                aR[r][0] = *(const float4*)&hrec[r][kg * 12];
                aR[r][1] = *(const float4*)&hrec[r][kg * 12 + 4];
            }
#pragma unroll
            for (int kk = 0; kk < 8; kk++) {
                float4 w0 = wq[(size_t)(32 + kk * 4 + 0) * 64];
                float4 w1 = wq[(size_t)(32 + kk * 4 + 1) * 64];
                float4 w2 = wq[(size_t)(32 + kk * 4 + 2) * 64];
                float4 w3 = wq[(size_t)(32 + kk * 4 + 3) * 64];
#pragma unroll
                for (int r = 0; r < 4; r++) {
                    float a = f4c(aR[r][kk >> 2], kk);
                    FMA4(acc[r * 4 + 0], a, w0); FMA4(acc[r * 4 + 1], a, w1);
                    FMA4(acc[r * 4 + 2], a, w2); FMA4(acc[r * 4 + 3], a, w3);
                }
            }
        }

        // ---- complete staging (tags ARE the ready-signal; usually instant) ----
        if (layer > 0) {
            while ((u32)(hv >> 32) != expseq) hv = ld_u64_agent(src);
            sAin[sr][s_lds] = __uint_as_float((u32)hv);
        } else if (tid < 32) {
            int r = tid >> 3, i = tid & 7;
            sAin[r][i] = xv;
        }
        __syncthreads();   // barA: staging done

        // publish staged-progress (my reads of seq s-1 complete); poll consumer's
        // staged-flag for the depth-4 anti-dep, overlapped with the ih-half
        // (guards only this slot's h-stores, which happen after barB).
        if (tid == 0) {
            if (myflag != nullptr)
                __hip_atomic_store(myflag, s, __ATOMIC_RELAXED, __HIP_MEMORY_SCOPE_AGENT);
            if (depflag != nullptr) {
                const int target = s - 3;
                while (__hip_atomic_load(depflag, __ATOMIC_RELAXED, __HIP_MEMORY_SCOPE_AGENT) < target)
                    __builtin_amdgcn_s_sleep(1);
            }
        }

        // ---- ih-half from staged sAin ----
        {
            float4 aR[4][2];
#pragma unroll
            for (int r = 0; r < 4; r++) {
                aR[r][0] = *(const float4*)&sAin[r][kg * 12];
                aR[r][1] = *(const float4*)&sAin[r][kg * 12 + 4];
            }
#pragma unroll
            for (int kk = 0; kk < 8; kk++) {
                float4 w0 = wq[(size_t)(kk * 4 + 0) * 64];
                float4 w1 = wq[(size_t)(kk * 4 + 1) * 64];
                float4 w2 = wq[(size_t)(kk * 4 + 2) * 64];
                float4 w3 = wq[(size_t)(kk * 4 + 3) * 64];
#pragma unroll
                for (int r = 0; r < 4; r++) {
                    float a = f4c(aR[r][kk >> 2], kk);
                    FMA4(acc[r * 4 + 0], a, w0); FMA4(acc[r * 4 + 1], a, w1);
                    FMA4(acc[r * 4 + 2], a, w2); FMA4(acc[r * 4 + 3], a, w3);
                }
            }
        }

        // ---- reduce across 16 kg lanes; root lane writes gates ----
#pragma unroll
        for (int i = 0; i < 16; i++) acc[i] = red16(acc[i]);
        if (kg == 15) {
#pragma unroll
            for (int r = 0; r < 4; r++)
#pragma unroll
                for (int cq = 0; cq < 4; cq++)
                    *(float4*)&sG[r][og * 16 + cq * 4] = acc[r * 4 + cq];
        }
        __syncthreads();   // barB: sG visible (and anti-dep poll complete)

        // ---- LSTM cell: 1 cell/thread; h -> LDS (recurrence) + sc1 (layer edge) ----
        {
            float gi = sG[ur][uc],        gf = sG[ur][128 + uc];
            float gg = sG[ur][256 + uc],  go = sG[ur][384 + uc];
            float si = 1.f / (1.f + __expf(-gi));
            float sf = 1.f / (1.f + __expf(-gf));
            float so = 1.f / (1.f + __expf(-go));
            creg = sf * creg + si * fast_tanh(gg);
            float h = so * fast_tanh(creg);
            hrec[ur][u_lds] = h;
            if (layer < 2 || t == Tt - 1) {
                u64* dst = hbuf + ((size_t)cur * 3 + layer) * Bsz * Hh
                         + (size_t)(r0 + ur) * Hh + uc;
                st_h_agent(dst, h, (u32)s);
            }
        }
        __syncthreads();   // barC: hrec ready for next slot's rec-half
    }
}

__global__ void fc_kernel(const float* __restrict__ ws, const float* __restrict__ Wfc,
                          const float* __restrict__ bfc, float* __restrict__ out)
{
    // final h of layer2 written at s=513 -> 513&3 = 1 -> hbuf[1][2]
    const u64* h2 = (const u64*)(ws + OFF_HBUF) + (size_t)(1 * 3 + 2) * Bsz * Hh;
    int b = threadIdx.x;   // 256 threads
    float a0 = bfc[0], a1 = bfc[1], a2 = bfc[2];
    for (int k = 0; k < 128; k++) {
        float h = __uint_as_float((u32)h2[b * 128 + k]);
        a0 += h * Wfc[0 * 128 + k];
        a1 += h * Wfc[1 * 128 + k];
        a2 += h * Wfc[2 * 128 + k];
    }
    out[b * 3 + 0] = a0;
    out[b * 3 + 1] = a1;
    out[b * 3 + 2] = a2;
}

extern "C" void kernel_launch(void* const* d_in, const int* in_sizes, int n_in,
                              void* d_out, int out_size, void* d_ws, size_t ws_size,
                              hipStream_t stream)
{
    const float* x = (const float*)d_in[0];
    float* ws = (float*)d_ws;

    prep_kernel<<<384, 256, 0, stream>>>(
        (const float*)d_in[1],  (const float*)d_in[2],  (const float*)d_in[3],  (const float*)d_in[4],
        (const float*)d_in[5],  (const float*)d_in[6],  (const float*)d_in[7],  (const float*)d_in[8],
        (const float*)d_in[9],  (const float*)d_in[10], (const float*)d_in[11], (const float*)d_in[12],
        ws);

    // cooperative launch solely for the co-residency guarantee (no grid.sync inside)
    void* args[2] = { (void*)&x, (void*)&ws };
    hipLaunchCooperativeKernel((void*)lstm_kernel, dim3(192), dim3(512), args, 0, stream);

    fc_kernel<<<1, 256, 0, stream>>>(ws, (const float*)d_in[13], (const float*)d_in[14], (float*)d_out);
}

// Round 13
// 3382.639 us; speedup vs baseline: 2.7758x; 2.7758x over previous
//
#include <hip/hip_runtime.h>

#define Bsz 256
#define Tt  512
#define Hh  128

// ws layout (floats):
//   Wt_ih [3][128][512]      k-major plain input weights (zero-filled k>=Kin)
//   Wt_hh [3][128][512]      k-major plain recurrent weights
//   bias  [3][512]           bih + bhh
//   hbuf  u64[4][3][256][128] 4-deep hidden states, (seq<<32)|bits(h)  (sc1 path)
//   flags [3][16][4] x 32    staging-progress flags (anti-dep only), 128B apart
#define OFF_WTHH 196608            // 3*128*512
#define OFF_BIAS 393216            // 2*196608
#define OFF_HBUF 394752            // + 3*512   (u64 array = 786432 floats)
#define OFF_FLAG 1181184           // + 786432
#define FLAG_N   6144              // 192 flags * 32 ints (128B stride)
// total used: 1187328 floats = 4.75 MB

// swizzled A-tile column: k -> (k>>3)*12 + (k&7); 8-float k-groups at 48 B stride
// -> 16 wave-distinct addrs, 2-way max bank aliasing (free), 16B-aligned b128 reads.
#define SKG(k) ((((k) >> 3) * 12) + ((k) & 7))

typedef unsigned long long u64;
typedef unsigned int u32;

// ---- MALL-coherent (sc0 sc1 per-access) relaxed agent-scope atomics ----
__device__ __forceinline__ void st_h_agent(u64* p, float v, u32 seq) {
    u64 u = ((u64)seq << 32) | (u64)__float_as_uint(v);
    __hip_atomic_store(p, u, __ATOMIC_RELAXED, __HIP_MEMORY_SCOPE_AGENT);
}
__device__ __forceinline__ u64 ld_u64_agent(const u64* p) {
    return __hip_atomic_load(p, __ATOMIC_RELAXED, __HIP_MEMORY_SCOPE_AGENT);
}

// stage 4 consecutive (val,seq) pairs; spin until all carry seq==exp.
// Exact-equality is safe (depth-4 anti-dep: producer can't overwrite until this
// block publishes its staged-flag, which happens only after this spin exits).
__device__ __forceinline__ float4 stage4(const u64* __restrict__ src, u32 exp) {
    u64 a, b, c, d;
    for (;;) {
        a = ld_u64_agent(src + 0);
        b = ld_u64_agent(src + 1);
        c = ld_u64_agent(src + 2);
        d = ld_u64_agent(src + 3);
        if ((u32)(a >> 32) == exp && (u32)(b >> 32) == exp &&
            (u32)(c >> 32) == exp && (u32)(d >> 32) == exp) break;
    }
    return make_float4(__uint_as_float((u32)a), __uint_as_float((u32)b),
                       __uint_as_float((u32)c), __uint_as_float((u32)d));
}

// fast tanh: 1 - 2/(e^{2x}+1); saturates correctly (verified r11, absmax 1.9e-6).
__device__ __forceinline__ float fast_tanh(float x) {
    float e = __expf(2.f * x);
    return 1.f - 2.f / (e + 1.f);
}

// VALU-pipe partial-row reduction: lane 15 of each 16-lane DPP row ends with the
// sum of lanes 0..15. bound_ctrl=1 -> 0-fill. (verified r4-r11)
template<int N>
__device__ __forceinline__ float row_shr_add(float v) {
    int s = __builtin_amdgcn_update_dpp(0, __float_as_int(v), 0x110 + N, 0xF, 0xF, true);
    return v + __int_as_float(s);
}
__device__ __forceinline__ float4 red16(float4 s) {
    s.x = row_shr_add<1>(s.x); s.x = row_shr_add<2>(s.x); s.x = row_shr_add<4>(s.x); s.x = row_shr_add<8>(s.x);
    s.y = row_shr_add<1>(s.y); s.y = row_shr_add<2>(s.y); s.y = row_shr_add<4>(s.y); s.y = row_shr_add<8>(s.y);
    s.z = row_shr_add<1>(s.z); s.z = row_shr_add<2>(s.z); s.z = row_shr_add<4>(s.z); s.z = row_shr_add<8>(s.z);
    s.w = row_shr_add<1>(s.w); s.w = row_shr_add<2>(s.w); s.w = row_shr_add<4>(s.w); s.w = row_shr_add<8>(s.w);
    return s;
}

#define FMA4(S, A, W) { S.x = fmaf(A, W.x, S.x); S.y = fmaf(A, W.y, S.y); \
                        S.z = fmaf(A, W.z, S.z); S.w = fmaf(A, W.w, S.w); }

__global__ void prep_kernel(const float* Wih0, const float* Whh0, const float* bih0, const float* bhh0,
                            const float* Wih1, const float* Whh1, const float* bih1, const float* bhh1,
                            const float* Wih2, const float* Whh2, const float* bih2, const float* bhh2,
                            float* ws)
{
    int gid = blockIdx.x * blockDim.x + threadIdx.x;   // 24*256 = 6144 threads
    if (gid < FLAG_N) ((int*)(ws + OFF_FLAG))[gid] = -1;      // anti-dep flags
    u64* hb = (u64*)(ws + OFF_HBUF);                          // seq init: never matches
    for (int i = gid; i < 4 * 3 * 256 * 128; i += 6144) hb[i] = 0xFFFFFFFF00000000ull;
    if (gid >= 3 * 512) return;
    int l = gid >> 9, gc = gid & 511;
    const float* Wih = (l == 0) ? Wih0 : (l == 1) ? Wih1 : Wih2;
    const float* Whh = (l == 0) ? Whh0 : (l == 1) ? Whh1 : Whh2;
    const float* bih = (l == 0) ? bih0 : (l == 1) ? bih1 : bih2;
    const float* bhh = (l == 0) ? bhh0 : (l == 1) ? bhh1 : bhh2;
    int Kin = (l == 0) ? 8 : 128;
    float* Wt_ih = ws + (size_t)l * 128 * 512;
    float* Wt_hh = ws + OFF_WTHH + (size_t)l * 128 * 512;
    float* bias  = ws + OFF_BIAS + l * 512;
    for (int k = 0; k < 128; k++) Wt_ih[k * 512 + gc] = (k < Kin) ? Wih[gc * Kin + k] : 0.f;
    for (int k = 0; k < 128; k++) Wt_hh[k * 512 + gc] = Whh[gc * 128 + k];
    bias[gc] = bih[gc] + bhh[gc];
}

// Persistent kernel, 192 blocks x 512 threads (verified r7/r11 partition & protocol).
// block = (layer, rtile, hctile); software wavefront t = s - layer.
// PIPELINED SLOT (new vs r11): the sibling-h MALL handoff (the true recurrence
// latency) is hidden under the ih-half GEMM:
//   issue sArec tag-loads -> stage sAin -> barA1 -> ih-half FMA (acc[8][2] regs)
//   -> finish sArec spin (data has had ~1.2us to land) -> barA2 -> flag publish
//   + overlapped anti-dep poll -> rec-half FMA -> reduce -> barB -> cell.
// Summation order per element: bias, ih k-ascending, rec k-ascending -- identical
// to r11 -> bit-identical numerics.
__global__ __launch_bounds__(512, 2) void lstm_kernel(const float* __restrict__ x,
                                                      float* __restrict__ ws)
{
    const float* __restrict__ bias = ws + OFF_BIAS;
    u64* __restrict__ hbuf = (u64*)(ws + OFF_HBUF);
    int* __restrict__ fl = (int*)(ws + OFF_FLAG);

    const int layer = blockIdx.x >> 6;
    const int tile  = blockIdx.x & 63;
    const int rt  = tile & 15;
    const int hct = tile >> 4;
    const int r0  = rt << 4;            // batch rows [r0, r0+16)
    const int hc0 = hct << 5;           // hidden cols [hc0, hc0+32)
    const int tid = threadIdx.x;

    __shared__ float sAin[16][192];
    __shared__ float sArec[16][192];
    __shared__ float sG[16][132];

    // zero-fill sAin (layer0 reads k>=8 against zero weights; must not be garbage)
    for (int i = tid; i < 16 * 192; i += 512) ((float*)sAin)[i] = 0.f;

    // ---- anti-dep pollers: consumers of my slot s-4 data must have staged s-3 ----
    // tid 0..3: own-layer siblings (recurrent readers); tid 4..7: downstream layer.
    int* adflag = nullptr;
    if (tid < 4)                    adflag = fl + ((layer * 16 + rt) * 4 + tid) * 32;
    else if (tid < 8 && layer < 2)  adflag = fl + (((layer + 1) * 16 + rt) * 4 + (tid - 4)) * 32;
    int* myflag = fl + ((layer * 16 + rt) * 4 + hct) * 32;

    // ---- thread tile ----
    const int kg = tid & 15;               // k-group (DPP-row lane 0..15)
    const int rg = (tid >> 4) & 1;         // row half: rows rg*8 .. rg*8+7
    const int cg = tid >> 5;               // col-group 0..15
    const int cbase = cg << 3;             // block-local col 0..120 (8 cols, same gate)
    const int gcb = ((cbase >> 5) << 7) + hc0 + (cbase & 31);   // global gate col
    const int ka = kg * 12;                // swizzled A base for this k-slice

    // ---- load weights into registers (once): 32 float4 ----
    const float* Wl_ih = ws + (size_t)layer * 65536;
    const float* Wl_hh = ws + OFF_WTHH + (size_t)layer * 65536;
    float4 wihA[8], wihB[8], whhA[8], whhB[8];
#pragma unroll
    for (int kk = 0; kk < 8; kk++) {
        int k = kg * 8 + kk;
        wihA[kk] = *(const float4*)&Wl_ih[(size_t)k * 512 + gcb];
        wihB[kk] = *(const float4*)&Wl_ih[(size_t)k * 512 + gcb + 4];
        whhA[kk] = *(const float4*)&Wl_hh[(size_t)k * 512 + gcb];
        whhB[kk] = *(const float4*)&Wl_hh[(size_t)k * 512 + gcb + 4];
    }
    float4 bias4a = *(const float4*)&bias[layer * 512 + gcb];
    float4 bias4b = *(const float4*)&bias[layer * 512 + gcb + 4];
    if (kg != 15) {   // bias added exactly once per col (at the reduction root lane)
        bias4a = make_float4(0.f, 0.f, 0.f, 0.f);
        bias4b = make_float4(0.f, 0.f, 0.f, 0.f);
    }

    // staging coords: 32 threads/row x 4 floats
    const int sr = tid >> 5;               // 0..15
    const int sk = (tid & 31) << 2;        // 0,4,...,124
    const int skc = SKG(sk);

    // cell-update coords: 1 cell/thread
    const int ur = tid >> 5, uc = tid & 31;
    float creg = 0.f;

    __syncthreads();   // sAin zero-fill visible

    for (int t = 0; t < Tt; ++t) {
        const int s = t + layer;
        const int prev = (s - 1) & 3, cur = s & 3;   // depth-4 buffering
        const u32 expseq = (u32)(s - 1);

        // ---- (1) ISSUE sArec tag-loads early (fire-and-forget; land under ih FMA) ----
        const u64* srcR = hbuf + ((size_t)prev * 3 + layer) * Bsz * Hh
                        + (size_t)(r0 + sr) * Hh + sk;
        u64 b0 = 0, b1 = 0, b2 = 0, b3 = 0;
        if (t > 0) {
            b0 = ld_u64_agent(srcR + 0); b1 = ld_u64_agent(srcR + 1);
            b2 = ld_u64_agent(srcR + 2); b3 = ld_u64_agent(srcR + 3);
        }

        // ---- (2) stage sAin (near-instant: cross-layer slack or x) ----
        if (layer == 0) {
            if (tid < 128) {
                int r = tid >> 3, i = tid & 7;
                sAin[r][i] = x[((size_t)(r0 + r) * Tt + t) * 8 + i];
            }
        } else {
            const u64* srcA = hbuf + ((size_t)prev * 3 + (layer - 1)) * Bsz * Hh
                            + (size_t)(r0 + sr) * Hh + sk;
            *(float4*)&sAin[sr][skc] = stage4(srcA, expseq);
        }
        __syncthreads();   // barA1: sAin staged

        // ---- (3) ih-half GEMM into held accumulators (hides sArec handoff) ----
        float4 acc[8][2];
#pragma unroll
        for (int j = 0; j < 8; j++) { acc[j][0] = bias4a; acc[j][1] = bias4b; }
#pragma unroll
        for (int j = 0; j < 8; j++) {
            const int r = rg * 8 + j;
            float4 a0 = *(const float4*)&sAin[r][ka];
            float4 a1 = *(const float4*)&sAin[r][ka + 4];
            FMA4(acc[j][0], a0.x, wihA[0]); FMA4(acc[j][1], a0.x, wihB[0]);
            FMA4(acc[j][0], a0.y, wihA[1]); FMA4(acc[j][1], a0.y, wihB[1]);
            FMA4(acc[j][0], a0.z, wihA[2]); FMA4(acc[j][1], a0.z, wihB[2]);
            FMA4(acc[j][0], a0.w, wihA[3]); FMA4(acc[j][1], a0.w, wihB[3]);
            FMA4(acc[j][0], a1.x, wihA[4]); FMA4(acc[j][1], a1.x, wihB[4]);
            FMA4(acc[j][0], a1.y, wihA[5]); FMA4(acc[j][1], a1.y, wihB[5]);
            FMA4(acc[j][0], a1.z, wihA[6]); FMA4(acc[j][1], a1.z, wihB[6]);
            FMA4(acc[j][0], a1.w, wihA[7]); FMA4(acc[j][1], a1.w, wihB[7]);
        }

        // ---- (4) complete sArec staging (tags usually already landed) ----
        if (t > 0) {
            while ((u32)(b0 >> 32) != expseq || (u32)(b1 >> 32) != expseq ||
                   (u32)(b2 >> 32) != expseq || (u32)(b3 >> 32) != expseq) {
                b0 = ld_u64_agent(srcR + 0); b1 = ld_u64_agent(srcR + 1);
                b2 = ld_u64_agent(srcR + 2); b3 = ld_u64_agent(srcR + 3);
            }
            *(float4*)&sArec[sr][skc] = make_float4(
                __uint_as_float((u32)b0), __uint_as_float((u32)b1),
                __uint_as_float((u32)b2), __uint_as_float((u32)b3));
        }
        __syncthreads();   // barA2: all staging done

        // publish "staged slot s" (both streams' tags s-1 consumed)
        if (tid == 0)
            __hip_atomic_store(myflag, s, __ATOMIC_RELAXED, __HIP_MEMORY_SCOPE_AGENT);

        // anti-dep poll, OVERLAPPED with rec-half (guards only this slot's h-stores,
        // which happen after barB; s_sleep keeps the 8 pollers off the issue ports).
        if (adflag != nullptr) {
            const int target = s - 3;
            while (__hip_atomic_load(adflag, __ATOMIC_RELAXED, __HIP_MEMORY_SCOPE_AGENT) < target)
                __builtin_amdgcn_s_sleep(1);
        }

        // ---- (5) rec-half GEMM ----
        if (t > 0) {
#pragma unroll
            for (int j = 0; j < 8; j++) {
                const int r = rg * 8 + j;
                float4 c0 = *(const float4*)&sArec[r][ka];
                float4 c1 = *(const float4*)&sArec[r][ka + 4];
                FMA4(acc[j][0], c0.x, whhA[0]); FMA4(acc[j][1], c0.x, whhB[0]);
                FMA4(acc[j][0], c0.y, whhA[1]); FMA4(acc[j][1], c0.y, whhB[1]);
                FMA4(acc[j][0], c0.z, whhA[2]); FMA4(acc[j][1], c0.z, whhB[2]);
                FMA4(acc[j][0], c0.w, whhA[3]); FMA4(acc[j][1], c0.w, whhB[3]);
                FMA4(acc[j][0], c1.x, whhA[4]); FMA4(acc[j][1], c1.x, whhB[4]);
                FMA4(acc[j][0], c1.y, whhA[5]); FMA4(acc[j][1], c1.y, whhB[5]);
                FMA4(acc[j][0], c1.z, whhA[6]); FMA4(acc[j][1], c1.z, whhB[6]);
                FMA4(acc[j][0], c1.w, whhA[7]); FMA4(acc[j][1], c1.w, whhB[7]);
            }
        }

        // ---- (6) reduce across 16 kg lanes; root lane writes gates ----
#pragma unroll
        for (int j = 0; j < 8; j++) {
            float4 r0v = red16(acc[j][0]);
            float4 r1v = red16(acc[j][1]);
            if (kg == 15) {
                *(float4*)&sG[rg * 8 + j][cbase]     = r0v;
                *(float4*)&sG[rg * 8 + j][cbase + 4] = r1v;
            }
        }
        __syncthreads();   // barB: sG visible (and anti-dep poll complete)

        // ---- (7) LSTM cell: 1 cell/thread; store (h,seq) -- the signal itself ----
        {
            float gi = sG[ur][uc],      gf = sG[ur][32 + uc];
            float gg = sG[ur][64 + uc], go = sG[ur][96 + uc];
            float si = 1.f / (1.f + __expf(-gi));
            float sf = 1.f / (1.f + __expf(-gf));
            float so = 1.f / (1.f + __expf(-go));
            creg = sf * creg + si * fast_tanh(gg);
            u64* dst = hbuf + ((size_t)cur * 3 + layer) * Bsz * Hh
                     + (size_t)(r0 + ur) * Hh + hc0 + uc;
            st_h_agent(dst, so * fast_tanh(creg), (u32)s);
        }
        // no trailing barrier: next slot's LDS writes are ordered by barA1/barA2.
    }
}

__global__ void fc_kernel(const float* __restrict__ ws, const float* __restrict__ Wfc,
                          const float* __restrict__ bfc, float* __restrict__ out)
{
    // final h of layer2 written at s=513 -> 513&3 = 1 -> hbuf[1][2]
    const u64* h2 = (const u64*)(ws + OFF_HBUF) + (size_t)(1 * 3 + 2) * Bsz * Hh;
    int b = threadIdx.x;   // 256 threads
    float a0 = bfc[0], a1 = bfc[1], a2 = bfc[2];
    for (int k = 0; k < 128; k++) {
        float h = __uint_as_float((u32)h2[b * 128 + k]);
        a0 += h * Wfc[0 * 128 + k];
        a1 += h * Wfc[1 * 128 + k];
        a2 += h * Wfc[2 * 128 + k];
    }
    out[b * 3 + 0] = a0;
    out[b * 3 + 1] = a1;
    out[b * 3 + 2] = a2;
}

extern "C" void kernel_launch(void* const* d_in, const int* in_sizes, int n_in,
                              void* d_out, int out_size, void* d_ws, size_t ws_size,
                              hipStream_t stream)
{
    const float* x = (const float*)d_in[0];
    float* ws = (float*)d_ws;

    prep_kernel<<<24, 256, 0, stream>>>(
        (const float*)d_in[1],  (const float*)d_in[2],  (const float*)d_in[3],  (const float*)d_in[4],
        (const float*)d_in[5],  (const float*)d_in[6],  (const float*)d_in[7],  (const float*)d_in[8],
        (const float*)d_in[9],  (const float*)d_in[10], (const float*)d_in[11], (const float*)d_in[12],
        ws);

    // cooperative launch solely for the co-residency guarantee (no grid.sync inside)
    void* args[2] = { (void*)&x, (void*)&ws };
    hipLaunchCooperativeKernel((void*)lstm_kernel, dim3(192), dim3(512), args, 0, stream);

    fc_kernel<<<1, 256, 0, stream>>>(ws, (const float*)d_in[13], (const float*)d_in[14], (float*)d_out);
}

// Round 14
// 3278.174 us; speedup vs baseline: 2.8642x; 1.0319x over previous
//
#include <hip/hip_runtime.h>

#define Bsz 256
#define Tt  512
#define Hh  128

// ws layout (floats):
//   Wt_ih [3][128][512]      k-major plain input weights (zero-filled k>=Kin)
//   Wt_hh [3][128][512]      k-major plain recurrent weights
//   bias  [3][512]           bih + bhh
//   hbuf  u64[4][3][256][128] 4-deep hidden states, (seq<<32)|bits(h)  (sc1 path)
//   flags [3][16][4] x 32    staging-progress flags (anti-dep only), 128B apart
#define OFF_WTHH 196608            // 3*128*512
#define OFF_BIAS 393216            // 2*196608
#define OFF_HBUF 394752            // + 3*512   (u64 array = 786432 floats)
#define OFF_FLAG 1181184           // + 786432
#define FLAG_N   6144              // 192 flags * 32 ints (128B stride)
// total used: 1187328 floats = 4.75 MB

// swizzled A-tile column: k -> (k>>3)*12 + (k&7); 8-float k-groups at 48 B stride
// -> 16 wave-distinct addrs, 2-way max bank aliasing (free), 16B-aligned b128 reads.
#define SKG(k) ((((k) >> 3) * 12) + ((k) & 7))

typedef unsigned long long u64;
typedef unsigned int u32;

// ---- MALL-coherent (sc0 sc1 per-access) relaxed agent-scope atomics ----
__device__ __forceinline__ void st_h_agent(u64* p, float v, u32 seq) {
    u64 u = ((u64)seq << 32) | (u64)__float_as_uint(v);
    __hip_atomic_store(p, u, __ATOMIC_RELAXED, __HIP_MEMORY_SCOPE_AGENT);
}
__device__ __forceinline__ u64 ld_u64_agent(const u64* p) {
    return __hip_atomic_load(p, __ATOMIC_RELAXED, __HIP_MEMORY_SCOPE_AGENT);
}

// stage 4 consecutive (val,seq) pairs; spin until all carry seq==exp.
// The data IS the ready-signal: no flag round trip on the critical cycle.
// Exact-equality is safe: the producer cannot overwrite this buffer slot with a
// later seq until THIS block publishes its staged-flag (depth-4 anti-dep).
__device__ __forceinline__ float4 stage4(const u64* __restrict__ src, u32 exp) {
    u64 a, b, c, d;
    for (;;) {
        a = ld_u64_agent(src + 0);
        b = ld_u64_agent(src + 1);
        c = ld_u64_agent(src + 2);
        d = ld_u64_agent(src + 3);
        if ((u32)(a >> 32) == exp && (u32)(b >> 32) == exp &&
            (u32)(c >> 32) == exp && (u32)(d >> 32) == exp) break;
    }
    return make_float4(__uint_as_float((u32)a), __uint_as_float((u32)b),
                       __uint_as_float((u32)c), __uint_as_float((u32)d));
}

// VALU-pipe partial-row reduction: lane 15 of each 16-lane DPP row ends with the
// sum of lanes 0..15. bound_ctrl=1 -> 0-fill.
template<int N>
__device__ __forceinline__ float row_shr_add(float v) {
    int s = __builtin_amdgcn_update_dpp(0, __float_as_int(v), 0x110 + N, 0xF, 0xF, true);
    return v + __int_as_float(s);
}
__device__ __forceinline__ float4 red16(float4 s) {
    s.x = row_shr_add<1>(s.x); s.x = row_shr_add<2>(s.x); s.x = row_shr_add<4>(s.x); s.x = row_shr_add<8>(s.x);
    s.y = row_shr_add<1>(s.y); s.y = row_shr_add<2>(s.y); s.y = row_shr_add<4>(s.y); s.y = row_shr_add<8>(s.y);
    s.z = row_shr_add<1>(s.z); s.z = row_shr_add<2>(s.z); s.z = row_shr_add<4>(s.z); s.z = row_shr_add<8>(s.z);
    s.w = row_shr_add<1>(s.w); s.w = row_shr_add<2>(s.w); s.w = row_shr_add<4>(s.w); s.w = row_shr_add<8>(s.w);
    return s;
}

#define FMA4(S, A, W) { S.x = fmaf(A, W.x, S.x); S.y = fmaf(A, W.y, S.y); \
                        S.z = fmaf(A, W.z, S.z); S.w = fmaf(A, W.w, S.w); }

__global__ void prep_kernel(const float* Wih0, const float* Whh0, const float* bih0, const float* bhh0,
                            const float* Wih1, const float* Whh1, const float* bih1, const float* bhh1,
                            const float* Wih2, const float* Whh2, const float* bih2, const float* bhh2,
                            float* ws)
{
    int gid = blockIdx.x * blockDim.x + threadIdx.x;   // 24*256 = 6144 threads
    if (gid < FLAG_N) ((int*)(ws + OFF_FLAG))[gid] = -1;      // anti-dep flags
    u64* hb = (u64*)(ws + OFF_HBUF);                          // seq init: never matches
    for (int i = gid; i < 4 * 3 * 256 * 128; i += 6144) hb[i] = 0xFFFFFFFF00000000ull;
    if (gid >= 3 * 512) return;
    int l = gid >> 9, gc = gid & 511;
    const float* Wih = (l == 0) ? Wih0 : (l == 1) ? Wih1 : Wih2;
    const float* Whh = (l == 0) ? Whh0 : (l == 1) ? Whh1 : Whh2;
    const float* bih = (l == 0) ? bih0 : (l == 1) ? bih1 : bih2;
    const float* bhh = (l == 0) ? bhh0 : (l == 1) ? bhh1 : bhh2;
    int Kin = (l == 0) ? 8 : 128;
    float* Wt_ih = ws + (size_t)l * 128 * 512;
    float* Wt_hh = ws + OFF_WTHH + (size_t)l * 128 * 512;
    float* bias  = ws + OFF_BIAS + l * 512;
    for (int k = 0; k < 128; k++) Wt_ih[k * 512 + gc] = (k < Kin) ? Wih[gc * Kin + k] : 0.f;
    for (int k = 0; k < 128; k++) Wt_hh[k * 512 + gc] = Whh[gc * 128 + k];
    bias[gc] = bih[gc] + bhh[gc];
}

// Persistent kernel, 192 blocks x 512 threads (8 waves -> 2 waves/SIMD).
// block = (layer, rtile, hctile); software wavefront t = s - layer.
// Readiness travels IN the h data (seq-tagged u64); flags only guard the depth-4
// buffer anti-dependence (target s-3, checked overlapped at slot start).
// 2 barriers per slot: barA (staging done) and barB (sG ready).
// [Session-verified best: 3168us. Structural probes beyond this (r8 pin, r9 TLP
// retile, r11 latency trims, r12 block-local recurrence, r13 slot pipelining)
// were all neutral, negative, or incorrect -- this is the floor of the
// wavefront+seq-tag structure family; residual ~3.7us/slot is distributed
// barrier-convoy + MALL-exchange latency, not attackable by slot reordering.]
__global__ __launch_bounds__(512, 2) void lstm_kernel(const float* __restrict__ x,
                                                      float* __restrict__ ws)
{
    const float* __restrict__ bias = ws + OFF_BIAS;
    u64* __restrict__ hbuf = (u64*)(ws + OFF_HBUF);
    int* __restrict__ fl = (int*)(ws + OFF_FLAG);

    const int layer = blockIdx.x >> 6;
    const int tile  = blockIdx.x & 63;
    const int rt  = tile & 15;
    const int hct = tile >> 4;
    const int r0  = rt << 4;            // batch rows [r0, r0+16)
    const int hc0 = hct << 5;           // hidden cols [hc0, hc0+32)
    const int tid = threadIdx.x;

    __shared__ float sAin[16][192];
    __shared__ float sArec[16][192];
    __shared__ float sG[16][132];

    // zero-fill sAin (layer0 reads k>=8 against zero weights; must not be garbage)
    for (int i = tid; i < 16 * 192; i += 512) ((float*)sAin)[i] = 0.f;

    // ---- anti-dep pollers: consumers of my slot s-4 data must have staged s-3 ----
    // tid 0..3: own-layer siblings (recurrent readers); tid 4..7: downstream layer.
    int* adflag = nullptr;
    if (tid < 4)                    adflag = fl + ((layer * 16 + rt) * 4 + tid) * 32;
    else if (tid < 8 && layer < 2)  adflag = fl + (((layer + 1) * 16 + rt) * 4 + (tid - 4)) * 32;
    int* myflag = fl + ((layer * 16 + rt) * 4 + hct) * 32;

    // ---- thread tile ----
    const int kg = tid & 15;               // k-group (DPP-row lane 0..15)
    const int rg = (tid >> 4) & 1;         // row half: rows rg*8 .. rg*8+7
    const int cg = tid >> 5;               // col-group 0..15
    const int cbase = cg << 3;             // block-local col 0..120 (8 cols, same gate)
    const int gcb = ((cbase >> 5) << 7) + hc0 + (cbase & 31);   // global gate col
    const int ka = kg * 12;                // swizzled A base for this k-slice

    // ---- load weights into registers (once): 32 float4 ----
    const float* Wl_ih = ws + (size_t)layer * 65536;
    const float* Wl_hh = ws + OFF_WTHH + (size_t)layer * 65536;
    float4 wihA[8], wihB[8], whhA[8], whhB[8];
#pragma unroll
    for (int kk = 0; kk < 8; kk++) {
        int k = kg * 8 + kk;
        wihA[kk] = *(const float4*)&Wl_ih[(size_t)k * 512 + gcb];
        wihB[kk] = *(const float4*)&Wl_ih[(size_t)k * 512 + gcb + 4];
        whhA[kk] = *(const float4*)&Wl_hh[(size_t)k * 512 + gcb];
        whhB[kk] = *(const float4*)&Wl_hh[(size_t)k * 512 + gcb + 4];
    }
    float4 bias4a = *(const float4*)&bias[layer * 512 + gcb];
    float4 bias4b = *(const float4*)&bias[layer * 512 + gcb + 4];
    if (kg != 15) {   // bias added exactly once per col (at the reduction root lane)
        bias4a = make_float4(0.f, 0.f, 0.f, 0.f);
        bias4b = make_float4(0.f, 0.f, 0.f, 0.f);
    }

    // staging coords: 32 threads/row x 4 floats
    const int sr = tid >> 5;               // 0..15
    const int sk = (tid & 31) << 2;        // 0,4,...,124
    const int skc = SKG(sk);

    // cell-update coords: 1 cell/thread
    const int ur = tid >> 5, uc = tid & 31;
    float creg = 0.f;

    __syncthreads();   // sAin zero-fill visible

    for (int t = 0; t < Tt; ++t) {
        const int s = t + layer;
        const int prev = (s - 1) & 3, cur = s & 3;   // depth-4 buffering
        const u32 expseq = (u32)(s - 1);

        // ---- anti-dep (depth-4 slack: target s-3; flags init -1 auto-pass early) ----
        if (adflag != nullptr) {
            const int target = s - 3;
            while (__hip_atomic_load(adflag, __ATOMIC_RELAXED, __HIP_MEMORY_SCOPE_AGENT) < target)
                ;
        }

        // ---- stage A tiles into LDS; the seq tags ARE the ready-signal ----
        if (layer == 0) {
            if (tid < 128) {
                int r = tid >> 3, i = tid & 7;
                sAin[r][i] = x[((size_t)(r0 + r) * Tt + t) * 8 + i];
            }
        } else {
            const u64* src = hbuf + ((size_t)prev * 3 + (layer - 1)) * Bsz * Hh
                           + (size_t)(r0 + sr) * Hh + sk;
            *(float4*)&sAin[sr][skc] = stage4(src, expseq);
        }
        if (t > 0) {
            const u64* src = hbuf + ((size_t)prev * 3 + layer) * Bsz * Hh
                           + (size_t)(r0 + sr) * Hh + sk;
            *(float4*)&sArec[sr][skc] = stage4(src, expseq);
        }
        __syncthreads();   // barA: staging done (also orders anti-dep poll before stores)

        // publish "staged slot s" (earliest legal point: my reads of s-1 are complete)
        if (tid == 0)
            __hip_atomic_store(myflag, s, __ATOMIC_RELAXED, __HIP_MEMORY_SCOPE_AGENT);

        // ---- GEMM: register weights x LDS A-slices (8 rows x 8 cols / thread) ----
#pragma unroll
        for (int j = 0; j < 8; j++) {
            const int r = rg * 8 + j;
            float4 acc0 = bias4a, acc1 = bias4b;
            {
                float4 a0 = *(const float4*)&sAin[r][ka];
                float4 a1 = *(const float4*)&sAin[r][ka + 4];
                FMA4(acc0, a0.x, wihA[0]); FMA4(acc1, a0.x, wihB[0]);
                FMA4(acc0, a0.y, wihA[1]); FMA4(acc1, a0.y, wihB[1]);
                FMA4(acc0, a0.z, wihA[2]); FMA4(acc1, a0.z, wihB[2]);
                FMA4(acc0, a0.w, wihA[3]); FMA4(acc1, a0.w, wihB[3]);
                FMA4(acc0, a1.x, wihA[4]); FMA4(acc1, a1.x, wihB[4]);
                FMA4(acc0, a1.y, wihA[5]); FMA4(acc1, a1.y, wihB[5]);
                FMA4(acc0, a1.z, wihA[6]); FMA4(acc1, a1.z, wihB[6]);
                FMA4(acc0, a1.w, wihA[7]); FMA4(acc1, a1.w, wihB[7]);
            }
            if (t > 0) {
                float4 b0 = *(const float4*)&sArec[r][ka];
                float4 b1 = *(const float4*)&sArec[r][ka + 4];
                FMA4(acc0, b0.x, whhA[0]); FMA4(acc1, b0.x, whhB[0]);
                FMA4(acc0, b0.y, whhA[1]); FMA4(acc1, b0.y, whhB[1]);
                FMA4(acc0, b0.z, whhA[2]); FMA4(acc1, b0.z, whhB[2]);
                FMA4(acc0, b0.w, whhA[3]); FMA4(acc1, b0.w, whhB[3]);
                FMA4(acc0, b1.x, whhA[4]); FMA4(acc1, b1.x, whhB[4]);
                FMA4(acc0, b1.y, whhA[5]); FMA4(acc1, b1.y, whhB[5]);
                FMA4(acc0, b1.z, whhA[6]); FMA4(acc1, b1.z, whhB[6]);
                FMA4(acc0, b1.w, whhA[7]); FMA4(acc1, b1.w, whhB[7]);
            }
            acc0 = red16(acc0);            // lane kg==15: full sum + bias
            acc1 = red16(acc1);
            if (kg == 15) {
                *(float4*)&sG[r][cbase]     = acc0;
                *(float4*)&sG[r][cbase + 4] = acc1;
            }
        }
        __syncthreads();   // barB: sG visible

        // ---- LSTM cell update: 1 cell/thread; store (h,seq) -- the signal itself ----
        {
            float gi = sG[ur][uc],      gf = sG[ur][32 + uc];
            float gg = sG[ur][64 + uc], go = sG[ur][96 + uc];
            float si = 1.f / (1.f + __expf(-gi));
            float sf = 1.f / (1.f + __expf(-gf));
            float so = 1.f / (1.f + __expf(-go));
            creg = sf * creg + si * tanhf(gg);
            u64* dst = hbuf + ((size_t)cur * 3 + layer) * Bsz * Hh
                     + (size_t)(r0 + ur) * Hh + hc0 + uc;
            st_h_agent(dst, so * tanhf(creg), (u32)s);
        }
        // no barrier: next-slot staging conflicts only with GEMM reads (ended at barB)
        // and cell's sG reads (ordered before next GEMM by next barA).
    }
}

__global__ void fc_kernel(const float* __restrict__ ws, const float* __restrict__ Wfc,
                          const float* __restrict__ bfc, float* __restrict__ out)
{
    // final h of layer2 written at s=513 -> 513&3 = 1 -> hbuf[1][2]
    const u64* h2 = (const u64*)(ws + OFF_HBUF) + (size_t)(1 * 3 + 2) * Bsz * Hh;
    int b = threadIdx.x;   // 256 threads
    float a0 = bfc[0], a1 = bfc[1], a2 = bfc[2];
    for (int k = 0; k < 128; k++) {
        float h = __uint_as_float((u32)h2[b * 128 + k]);
        a0 += h * Wfc[0 * 128 + k];
        a1 += h * Wfc[1 * 128 + k];
        a2 += h * Wfc[2 * 128 + k];
    }
    out[b * 3 + 0] = a0;
    out[b * 3 + 1] = a1;
    out[b * 3 + 2] = a2;
}

extern "C" void kernel_launch(void* const* d_in, const int* in_sizes, int n_in,
                              void* d_out, int out_size, void* d_ws, size_t ws_size,
                              hipStream_t stream)
{
    const float* x = (const float*)d_in[0];
    float* ws = (float*)d_ws;

    prep_kernel<<<24, 256, 0, stream>>>(
        (const float*)d_in[1],  (const float*)d_in[2],  (const float*)d_in[3],  (const float*)d_in[4],
        (const float*)d_in[5],  (const float*)d_in[6],  (const float*)d_in[7],  (const float*)d_in[8],
        (const float*)d_in[9],  (const float*)d_in[10], (const float*)d_in[11], (const float*)d_in[12],
        ws);

    // cooperative launch solely for the co-residency guarantee (no grid.sync inside)
    void* args[2] = { (void*)&x, (void*)&ws };
    hipLaunchCooperativeKernel((void*)lstm_kernel, dim3(192), dim3(512), args, 0, stream);

    fc_kernel<<<1, 256, 0, stream>>>(ws, (const float*)d_in[13], (const float*)d_in[14], (float*)d_out);
}

// Round 15
// 3273.915 us; speedup vs baseline: 2.8679x; 1.0013x over previous
//
#include <hip/hip_runtime.h>

#define Bsz 256
#define Tt  512
#define Hh  128

// ws layout (floats) -- identical to r7/r14:
//   Wt_ih [3][128][512]      k-major plain input weights (zero-filled k>=Kin)
//   Wt_hh [3][128][512]      k-major plain recurrent weights
//   bias  [3][512]           bih + bhh
//   hbuf  u64[4][3][256][128] 4-deep hidden states, (seq<<32)|bits(h)  (sc1 path)
//   flags [3][32][2] x 32    staging-progress flags (anti-dep only), 128B apart
#define OFF_WTHH 196608            // 3*128*512
#define OFF_BIAS 393216            // 2*196608
#define OFF_HBUF 394752            // + 3*512   (u64 array = 786432 floats)
#define OFF_FLAG 1181184           // + 786432
#define FLAG_N   6144              // 192 flags * 32 ints (128B stride)
// total used: 1187328 floats = 4.75 MB

// swizzled A-tile column: k -> (k>>3)*12 + (k&7); 8-float k-groups at 48 B stride
// -> 16 wave-distinct addrs, 2-way max bank aliasing (free), 16B-aligned b128 reads.
#define SKG(k) ((((k) >> 3) * 12) + ((k) & 7))

typedef unsigned long long u64;
typedef unsigned int u32;

// ---- MALL-coherent (sc0 sc1 per-access) relaxed agent-scope atomics ----
__device__ __forceinline__ void st_h_agent(u64* p, float v, u32 seq) {
    u64 u = ((u64)seq << 32) | (u64)__float_as_uint(v);
    __hip_atomic_store(p, u, __ATOMIC_RELAXED, __HIP_MEMORY_SCOPE_AGENT);
}
__device__ __forceinline__ u64 ld_u64_agent(const u64* p) {
    return __hip_atomic_load(p, __ATOMIC_RELAXED, __HIP_MEMORY_SCOPE_AGENT);
}

// stage 2 consecutive (val,seq) pairs; spin until both carry seq==exp.
// The data IS the ready-signal. Exact-equality safe: producer cannot overwrite
// this buffer slot until THIS block publishes its staged-flag (depth-4 anti-dep).
// Each thread's 2 values lie within ONE producer block's 64-col region.
__device__ __forceinline__ float2 stage2(const u64* __restrict__ src, u32 exp) {
    u64 a, b;
    for (;;) {
        a = ld_u64_agent(src + 0);
        b = ld_u64_agent(src + 1);
        if ((u32)(a >> 32) == exp && (u32)(b >> 32) == exp) break;
    }
    float2 r;
    r.x = __uint_as_float((u32)a);
    r.y = __uint_as_float((u32)b);
    return r;
}

// VALU-pipe partial-row reduction: lane 15 of each 16-lane DPP row ends with the
// sum of lanes 0..15. bound_ctrl=1 -> 0-fill. (verified r4-r14)
template<int N>
__device__ __forceinline__ float row_shr_add(float v) {
    int s = __builtin_amdgcn_update_dpp(0, __float_as_int(v), 0x110 + N, 0xF, 0xF, true);
    return v + __int_as_float(s);
}
__device__ __forceinline__ float4 red16(float4 s) {
    s.x = row_shr_add<1>(s.x); s.x = row_shr_add<2>(s.x); s.x = row_shr_add<4>(s.x); s.x = row_shr_add<8>(s.x);
    s.y = row_shr_add<1>(s.y); s.y = row_shr_add<2>(s.y); s.y = row_shr_add<4>(s.y); s.y = row_shr_add<8>(s.y);
    s.z = row_shr_add<1>(s.z); s.z = row_shr_add<2>(s.z); s.z = row_shr_add<4>(s.z); s.z = row_shr_add<8>(s.z);
    s.w = row_shr_add<1>(s.w); s.w = row_shr_add<2>(s.w); s.w = row_shr_add<4>(s.w); s.w = row_shr_add<8>(s.w);
    return s;
}

#define FMA4(S, A, W) { S.x = fmaf(A, W.x, S.x); S.y = fmaf(A, W.y, S.y); \
                        S.z = fmaf(A, W.z, S.z); S.w = fmaf(A, W.w, S.w); }

__global__ void prep_kernel(const float* Wih0, const float* Whh0, const float* bih0, const float* bhh0,
                            const float* Wih1, const float* Whh1, const float* bih1, const float* bhh1,
                            const float* Wih2, const float* Whh2, const float* bih2, const float* bhh2,
                            float* ws)
{
    int gid = blockIdx.x * blockDim.x + threadIdx.x;   // 24*256 = 6144 threads
    if (gid < FLAG_N) ((int*)(ws + OFF_FLAG))[gid] = -1;      // anti-dep flags
    u64* hb = (u64*)(ws + OFF_HBUF);                          // seq init: never matches
    for (int i = gid; i < 4 * 3 * 256 * 128; i += 6144) hb[i] = 0xFFFFFFFF00000000ull;
    if (gid >= 3 * 512) return;
    int l = gid >> 9, gc = gid & 511;
    const float* Wih = (l == 0) ? Wih0 : (l == 1) ? Wih1 : Wih2;
    const float* Whh = (l == 0) ? Whh0 : (l == 1) ? Whh1 : Whh2;
    const float* bih = (l == 0) ? bih0 : (l == 1) ? bih1 : bih2;
    const float* bhh = (l == 0) ? bhh0 : (l == 1) ? bhh1 : bhh2;
    int Kin = (l == 0) ? 8 : 128;
    float* Wt_ih = ws + (size_t)l * 128 * 512;
    float* Wt_hh = ws + OFF_WTHH + (size_t)l * 128 * 512;
    float* bias  = ws + OFF_BIAS + l * 512;
    for (int k = 0; k < 128; k++) Wt_ih[k * 512 + gc] = (k < Kin) ? Wih[gc * Kin + k] : 0.f;
    for (int k = 0; k < 128; k++) Wt_hh[k * 512 + gc] = Whh[gc * 128 + k];
    bias[gc] = bih[gc] + bhh[gc];
}

// Persistent kernel, 192 blocks x 512 threads (verified r7 protocol, RETILED).
// block = (layer, rt of 32, hct of 2): 8 batch rows x 64 hidden cols (256 gate
// cols). FAN-IN HALVED vs r7: own-layer producers 4->2, upstream 4->2, anti-dep
// consumers 8->4 -- r13's null showed the residual is max-of-producers TAIL
// latency, and this shrinks the max-set. Per-thread work is IDENTICAL to r7
// (kg16 x cg32: 8 rows x 8 cols x 8k x 2 matrices, 32 float4 reg weights,
// 32 ds_read_b128, same red16 tree) -> bit-identical numerics expected
// (absmax invariant 5.960464e-8 is the geometry tripwire).
__global__ __launch_bounds__(512, 2) void lstm_kernel(const float* __restrict__ x,
                                                      float* __restrict__ ws)
{
    const float* __restrict__ bias = ws + OFF_BIAS;
    u64* __restrict__ hbuf = (u64*)(ws + OFF_HBUF);
    int* __restrict__ fl = (int*)(ws + OFF_FLAG);

    const int layer = blockIdx.x >> 6;     // 0..2
    const int tile  = blockIdx.x & 63;
    const int rt  = tile >> 1;             // 0..31 (8 rows each)
    const int hct = tile & 1;              // 0..1  (64 hidden cols each)
    const int r0  = rt << 3;               // batch rows [r0, r0+8)
    const int hc0 = hct << 6;              // hidden cols [hc0, hc0+64)
    const int tid = threadIdx.x;

    __shared__ float sAin[8][192];
    __shared__ float sArec[8][192];
    __shared__ float sG[8][260];

    // zero-fill sAin (layer0 reads k>=8 against zero weights; must not be garbage)
    for (int i = tid; i < 8 * 192; i += 512) ((float*)sAin)[i] = 0.f;

    // ---- anti-dep pollers: consumers of my slot s-4 data must have staged s-3 ----
    // tid 0..1: own-layer blocks (recurrent readers, incl self); tid 2..3: downstream.
    int* adflag = nullptr;
    if (tid < 2)                    adflag = fl + ((layer * 32 + rt) * 2 + tid) * 32;
    else if (tid < 4 && layer < 2)  adflag = fl + (((layer + 1) * 32 + rt) * 2 + (tid - 2)) * 32;
    int* myflag = fl + ((layer * 32 + rt) * 2 + hct) * 32;

    // ---- thread tile: kg16 x cg32 -> 8 rows x 8 cols x (8k per matrix) ----
    const int kg = tid & 15;               // k-group (DPP-row lane 0..15)
    const int cg = tid >> 4;               // col-group 0..31
    const int cbase = cg << 3;             // block-local gate col 0..248 (8 cols)
    const int gcb = ((cbase >> 6) << 7) + hc0 + (cbase & 63);   // global gate col
    const int ka = kg * 12;                // swizzled A base for this k-slice

    // ---- load weights into registers (once): 32 float4 ----
    const float* Wl_ih = ws + (size_t)layer * 65536;
    const float* Wl_hh = ws + OFF_WTHH + (size_t)layer * 65536;
    float4 wihA[8], wihB[8], whhA[8], whhB[8];
#pragma unroll
    for (int kk = 0; kk < 8; kk++) {
        int k = kg * 8 + kk;
        wihA[kk] = *(const float4*)&Wl_ih[(size_t)k * 512 + gcb];
        wihB[kk] = *(const float4*)&Wl_ih[(size_t)k * 512 + gcb + 4];
        whhA[kk] = *(const float4*)&Wl_hh[(size_t)k * 512 + gcb];
        whhB[kk] = *(const float4*)&Wl_hh[(size_t)k * 512 + gcb + 4];
    }
    float4 bias4a = *(const float4*)&bias[layer * 512 + gcb];
    float4 bias4b = *(const float4*)&bias[layer * 512 + gcb + 4];
    if (kg != 15) {   // bias added exactly once per col (at the reduction root lane)
        bias4a = make_float4(0.f, 0.f, 0.f, 0.f);
        bias4b = make_float4(0.f, 0.f, 0.f, 0.f);
    }

    // staging coords: 64 threads/row x 2 u64 each (8 rows x 128 cols)
    const int sr = tid >> 6;               // 0..7
    const int sk = (tid & 63) << 1;        // 0,2,...,126
    const int skc = SKG(sk);               // pair stays contiguous (sk even)

    // cell-update coords: 1 cell/thread (8 rows x 64 hidden cols)
    const int ur = tid >> 6, uc = tid & 63;
    float creg = 0.f;

    __syncthreads();   // sAin zero-fill visible

    for (int t = 0; t < Tt; ++t) {
        const int s = t + layer;
        const int prev = (s - 1) & 3, cur = s & 3;   // depth-4 buffering
        const u32 expseq = (u32)(s - 1);

        // ---- anti-dep (depth-4 slack: target s-3; flags init -1 auto-pass early) ----
        if (adflag != nullptr) {
            const int target = s - 3;
            while (__hip_atomic_load(adflag, __ATOMIC_RELAXED, __HIP_MEMORY_SCOPE_AGENT) < target)
                ;
        }

        // ---- stage A tiles into LDS; the seq tags ARE the ready-signal ----
        if (layer == 0) {
            if (tid < 64) {
                int r = tid >> 3, i = tid & 7;
                sAin[r][i] = x[((size_t)(r0 + r) * Tt + t) * 8 + i];
            }
        } else {
            const u64* src = hbuf + ((size_t)prev * 3 + (layer - 1)) * Bsz * Hh
                           + (size_t)(r0 + sr) * Hh + sk;
            *(float2*)&sAin[sr][skc] = stage2(src, expseq);
        }
        if (t > 0) {
            const u64* src = hbuf + ((size_t)prev * 3 + layer) * Bsz * Hh
                           + (size_t)(r0 + sr) * Hh + sk;
            *(float2*)&sArec[sr][skc] = stage2(src, expseq);
        }
        __syncthreads();   // barA: staging done (also orders anti-dep poll before stores)

        // publish "staged slot s" (earliest legal point: my reads of s-1 are complete)
        if (tid == 0)
            __hip_atomic_store(myflag, s, __ATOMIC_RELAXED, __HIP_MEMORY_SCOPE_AGENT);

        // ---- GEMM: register weights x LDS A-slices (8 rows x 8 cols / thread) ----
#pragma unroll
        for (int r = 0; r < 8; r++) {
            float4 acc0 = bias4a, acc1 = bias4b;
            {
                float4 a0 = *(const float4*)&sAin[r][ka];
                float4 a1 = *(const float4*)&sAin[r][ka + 4];
                FMA4(acc0, a0.x, wihA[0]); FMA4(acc1, a0.x, wihB[0]);
                FMA4(acc0, a0.y, wihA[1]); FMA4(acc1, a0.y, wihB[1]);
                FMA4(acc0, a0.z, wihA[2]); FMA4(acc1, a0.z, wihB[2]);
                FMA4(acc0, a0.w, wihA[3]); FMA4(acc1, a0.w, wihB[3]);
                FMA4(acc0, a1.x, wihA[4]); FMA4(acc1, a1.x, wihB[4]);
                FMA4(acc0, a1.y, wihA[5]); FMA4(acc1, a1.y, wihB[5]);
                FMA4(acc0, a1.z, wihA[6]); FMA4(acc1, a1.z, wihB[6]);
                FMA4(acc0, a1.w, wihA[7]); FMA4(acc1, a1.w, wihB[7]);
            }
            if (t > 0) {
                float4 b0 = *(const float4*)&sArec[r][ka];
                float4 b1 = *(const float4*)&sArec[r][ka + 4];
                FMA4(acc0, b0.x, whhA[0]); FMA4(acc1, b0.x, whhB[0]);
                FMA4(acc0, b0.y, whhA[1]); FMA4(acc1, b0.y, whhB[1]);
                FMA4(acc0, b0.z, whhA[2]); FMA4(acc1, b0.z, whhB[2]);
                FMA4(acc0, b0.w, whhA[3]); FMA4(acc1, b0.w, whhB[3]);
                FMA4(acc0, b1.x, whhA[4]); FMA4(acc1, b1.x, whhB[4]);
                FMA4(acc0, b1.y, whhA[5]); FMA4(acc1, b1.y, whhB[5]);
                FMA4(acc0, b1.z, whhA[6]); FMA4(acc1, b1.z, whhB[6]);
                FMA4(acc0, b1.w, whhA[7]); FMA4(acc1, b1.w, whhB[7]);
            }
            acc0 = red16(acc0);            // lane kg==15: full sum + bias
            acc1 = red16(acc1);
            if (kg == 15) {
                *(float4*)&sG[r][cbase]     = acc0;
                *(float4*)&sG[r][cbase + 4] = acc1;
            }
        }
        __syncthreads();   // barB: sG visible

        // ---- LSTM cell update: 1 cell/thread; store (h,seq) -- the signal itself ----
        {
            float gi = sG[ur][uc],       gf = sG[ur][64 + uc];
            float gg = sG[ur][128 + uc], go = sG[ur][192 + uc];
            float si = 1.f / (1.f + __expf(-gi));
            float sf = 1.f / (1.f + __expf(-gf));
            float so = 1.f / (1.f + __expf(-go));
            creg = sf * creg + si * tanhf(gg);
            u64* dst = hbuf + ((size_t)cur * 3 + layer) * Bsz * Hh
                     + (size_t)(r0 + ur) * Hh + hc0 + uc;
            st_h_agent(dst, so * tanhf(creg), (u32)s);
        }
        // no barrier: next-slot staging conflicts only with GEMM reads (ended at barB)
        // and cell's sG reads (ordered before next GEMM by next barA).
    }
}

__global__ void fc_kernel(const float* __restrict__ ws, const float* __restrict__ Wfc,
                          const float* __restrict__ bfc, float* __restrict__ out)
{
    // final h of layer2 written at s=513 -> 513&3 = 1 -> hbuf[1][2]
    const u64* h2 = (const u64*)(ws + OFF_HBUF) + (size_t)(1 * 3 + 2) * Bsz * Hh;
    int b = threadIdx.x;   // 256 threads
    float a0 = bfc[0], a1 = bfc[1], a2 = bfc[2];
    for (int k = 0; k < 128; k++) {
        float h = __uint_as_float((u32)h2[b * 128 + k]);
        a0 += h * Wfc[0 * 128 + k];
        a1 += h * Wfc[1 * 128 + k];
        a2 += h * Wfc[2 * 128 + k];
    }
    out[b * 3 + 0] = a0;
    out[b * 3 + 1] = a1;
    out[b * 3 + 2] = a2;
}

extern "C" void kernel_launch(void* const* d_in, const int* in_sizes, int n_in,
                              void* d_out, int out_size, void* d_ws, size_t ws_size,
                              hipStream_t stream)
{
    const float* x = (const float*)d_in[0];
    float* ws = (float*)d_ws;

    prep_kernel<<<24, 256, 0, stream>>>(
        (const float*)d_in[1],  (const float*)d_in[2],  (const float*)d_in[3],  (const float*)d_in[4],
        (const float*)d_in[5],  (const float*)d_in[6],  (const float*)d_in[7],  (const float*)d_in[8],
        (const float*)d_in[9],  (const float*)d_in[10], (const float*)d_in[11], (const float*)d_in[12],
        ws);

    // cooperative launch solely for the co-residency guarantee (no grid.sync inside)
    void* args[2] = { (void*)&x, (void*)&ws };
    hipLaunchCooperativeKernel((void*)lstm_kernel, dim3(192), dim3(512), args, 0, stream);

    fc_kernel<<<1, 256, 0, stream>>>(ws, (const float*)d_in[13], (const float*)d_in[14], (float*)d_out);
}

// Round 16
// 3154.594 us; speedup vs baseline: 2.9764x; 1.0378x over previous
//
#include <hip/hip_runtime.h>

#define Bsz 256
#define Tt  512
#define Hh  128

// ws layout (floats):
//   Wt_ih [3][128][512]      k-major plain input weights (zero-filled k>=Kin)
//   Wt_hh [3][128][512]      k-major plain recurrent weights
//   bias  [3][512]           bih + bhh
//   hbuf  u64[4][3][256][128] 4-deep hidden states, (seq<<32)|bits(h)  (sc1 path)
//   flags [3][16][4] x 32    staging-progress flags (anti-dep only), 128B apart
#define OFF_WTHH 196608            // 3*128*512
#define OFF_BIAS 393216            // 2*196608
#define OFF_HBUF 394752            // + 3*512   (u64 array = 786432 floats)
#define OFF_FLAG 1181184           // + 786432
#define FLAG_N   6144              // 192 flags * 32 ints (128B stride)
// total used: 1187328 floats = 4.75 MB

// swizzled A-tile column: k -> (k>>3)*12 + (k&7); 8-float k-groups at 48 B stride
// -> 16 wave-distinct addrs, 2-way max bank aliasing (free), 16B-aligned b128 reads.
#define SKG(k) ((((k) >> 3) * 12) + ((k) & 7))

typedef unsigned long long u64;
typedef unsigned int u32;

// ---- MALL-coherent (sc0 sc1 per-access) relaxed agent-scope atomics ----
__device__ __forceinline__ void st_h_agent(u64* p, float v, u32 seq) {
    u64 u = ((u64)seq << 32) | (u64)__float_as_uint(v);
    __hip_atomic_store(p, u, __ATOMIC_RELAXED, __HIP_MEMORY_SCOPE_AGENT);
}
__device__ __forceinline__ u64 ld_u64_agent(const u64* p) {
    return __hip_atomic_load(p, __ATOMIC_RELAXED, __HIP_MEMORY_SCOPE_AGENT);
}

// stage 4 consecutive (val,seq) pairs; spin until all carry seq==exp.
// The data IS the ready-signal: no flag round trip on the critical cycle.
// Exact-equality is safe: the producer cannot overwrite this buffer slot with a
// later seq until THIS block publishes its staged-flag (depth-4 anti-dep).
__device__ __forceinline__ float4 stage4(const u64* __restrict__ src, u32 exp) {
    u64 a, b, c, d;
    for (;;) {
        a = ld_u64_agent(src + 0);
        b = ld_u64_agent(src + 1);
        c = ld_u64_agent(src + 2);
        d = ld_u64_agent(src + 3);
        if ((u32)(a >> 32) == exp && (u32)(b >> 32) == exp &&
            (u32)(c >> 32) == exp && (u32)(d >> 32) == exp) break;
    }
    return make_float4(__uint_as_float((u32)a), __uint_as_float((u32)b),
                       __uint_as_float((u32)c), __uint_as_float((u32)d));
}

// VALU-pipe partial-row reduction: lane 15 of each 16-lane DPP row ends with the
// sum of lanes 0..15. bound_ctrl=1 -> 0-fill.
template<int N>
__device__ __forceinline__ float row_shr_add(float v) {
    int s = __builtin_amdgcn_update_dpp(0, __float_as_int(v), 0x110 + N, 0xF, 0xF, true);
    return v + __int_as_float(s);
}
__device__ __forceinline__ float4 red16(float4 s) {
    s.x = row_shr_add<1>(s.x); s.x = row_shr_add<2>(s.x); s.x = row_shr_add<4>(s.x); s.x = row_shr_add<8>(s.x);
    s.y = row_shr_add<1>(s.y); s.y = row_shr_add<2>(s.y); s.y = row_shr_add<4>(s.y); s.y = row_shr_add<8>(s.y);
    s.z = row_shr_add<1>(s.z); s.z = row_shr_add<2>(s.z); s.z = row_shr_add<4>(s.z); s.z = row_shr_add<8>(s.z);
    s.w = row_shr_add<1>(s.w); s.w = row_shr_add<2>(s.w); s.w = row_shr_add<4>(s.w); s.w = row_shr_add<8>(s.w);
    return s;
}

#define FMA4(S, A, W) { S.x = fmaf(A, W.x, S.x); S.y = fmaf(A, W.y, S.y); \
                        S.z = fmaf(A, W.z, S.z); S.w = fmaf(A, W.w, S.w); }

__global__ void prep_kernel(const float* Wih0, const float* Whh0, const float* bih0, const float* bhh0,
                            const float* Wih1, const float* Whh1, const float* bih1, const float* bhh1,
                            const float* Wih2, const float* Whh2, const float* bih2, const float* bhh2,
                            float* ws)
{
    int gid = blockIdx.x * blockDim.x + threadIdx.x;   // 24*256 = 6144 threads
    if (gid < FLAG_N) ((int*)(ws + OFF_FLAG))[gid] = -1;      // anti-dep flags
    u64* hb = (u64*)(ws + OFF_HBUF);                          // seq init: never matches
    for (int i = gid; i < 4 * 3 * 256 * 128; i += 6144) hb[i] = 0xFFFFFFFF00000000ull;
    if (gid >= 3 * 512) return;
    int l = gid >> 9, gc = gid & 511;
    const float* Wih = (l == 0) ? Wih0 : (l == 1) ? Wih1 : Wih2;
    const float* Whh = (l == 0) ? Whh0 : (l == 1) ? Whh1 : Whh2;
    const float* bih = (l == 0) ? bih0 : (l == 1) ? bih1 : bih2;
    const float* bhh = (l == 0) ? bhh0 : (l == 1) ? bhh1 : bhh2;
    int Kin = (l == 0) ? 8 : 128;
    float* Wt_ih = ws + (size_t)l * 128 * 512;
    float* Wt_hh = ws + OFF_WTHH + (size_t)l * 128 * 512;
    float* bias  = ws + OFF_BIAS + l * 512;
    for (int k = 0; k < 128; k++) Wt_ih[k * 512 + gc] = (k < Kin) ? Wih[gc * Kin + k] : 0.f;
    for (int k = 0; k < 128; k++) Wt_hh[k * 512 + gc] = Whh[gc * 128 + k];
    bias[gc] = bih[gc] + bhh[gc];
}

// Persistent kernel, 192 blocks x 512 threads (8 waves -> 2 waves/SIMD).
// block = (layer, rtile, hctile); software wavefront t = s - layer.
// Readiness travels IN the h data (seq-tagged u64); flags only guard the depth-4
// buffer anti-dependence (target s-3, checked overlapped at slot start).
// 2 barriers per slot: barA (staging done) and barB (sG ready).
//
// [FINAL -- session-verified best (3168/3278us across two runs; 2.1x vs the
// 6672us session start). Structural probes beyond this (r8 register pin, r9
// 2-blocks/CU TLP retile, r11 detect-latency trims, r12 block-local recurrence
// with L2-streamed weights, r13 slot pipelining, r15 fan-in halving) were all
// neutral, negative, or incorrect. Per-slot ~6.3us = ~2.6us VALU (matches the
// 1024-FMA + DPP-reduce instruction count) + ~3.7us distributed MALL-exchange
// mean latency + barrier convoy over 514 sequential dependent slots. Not a
// hardware roofline (VALUBusy 42%, HBM 3%); the remaining lever (bf16x2-split
// MFMA GEMM) is a large unverified rewrite with payoff capped ~1.5x by the
// exchange floor.]
__global__ __launch_bounds__(512, 2) void lstm_kernel(const float* __restrict__ x,
                                                      float* __restrict__ ws)
{
    const float* __restrict__ bias = ws + OFF_BIAS;
    u64* __restrict__ hbuf = (u64*)(ws + OFF_HBUF);
    int* __restrict__ fl = (int*)(ws + OFF_FLAG);

    const int layer = blockIdx.x >> 6;
    const int tile  = blockIdx.x & 63;
    const int rt  = tile & 15;
    const int hct = tile >> 4;
    const int r0  = rt << 4;            // batch rows [r0, r0+16)
    const int hc0 = hct << 5;           // hidden cols [hc0, hc0+32)
    const int tid = threadIdx.x;

    __shared__ float sAin[16][192];
    __shared__ float sArec[16][192];
    __shared__ float sG[16][132];

    // zero-fill sAin (layer0 reads k>=8 against zero weights; must not be garbage)
    for (int i = tid; i < 16 * 192; i += 512) ((float*)sAin)[i] = 0.f;

    // ---- anti-dep pollers: consumers of my slot s-4 data must have staged s-3 ----
    // tid 0..3: own-layer siblings (recurrent readers); tid 4..7: downstream layer.
    int* adflag = nullptr;
    if (tid < 4)                    adflag = fl + ((layer * 16 + rt) * 4 + tid) * 32;
    else if (tid < 8 && layer < 2)  adflag = fl + (((layer + 1) * 16 + rt) * 4 + (tid - 4)) * 32;
    int* myflag = fl + ((layer * 16 + rt) * 4 + hct) * 32;

    // ---- thread tile ----
    const int kg = tid & 15;               // k-group (DPP-row lane 0..15)
    const int rg = (tid >> 4) & 1;         // row half: rows rg*8 .. rg*8+7
    const int cg = tid >> 5;               // col-group 0..15
    const int cbase = cg << 3;             // block-local col 0..120 (8 cols, same gate)
    const int gcb = ((cbase >> 5) << 7) + hc0 + (cbase & 31);   // global gate col
    const int ka = kg * 12;                // swizzled A base for this k-slice

    // ---- load weights into registers (once): 32 float4 ----
    const float* Wl_ih = ws + (size_t)layer * 65536;
    const float* Wl_hh = ws + OFF_WTHH + (size_t)layer * 65536;
    float4 wihA[8], wihB[8], whhA[8], whhB[8];
#pragma unroll
    for (int kk = 0; kk < 8; kk++) {
        int k = kg * 8 + kk;
        wihA[kk] = *(const float4*)&Wl_ih[(size_t)k * 512 + gcb];
        wihB[kk] = *(const float4*)&Wl_ih[(size_t)k * 512 + gcb + 4];
        whhA[kk] = *(const float4*)&Wl_hh[(size_t)k * 512 + gcb];
        whhB[kk] = *(const float4*)&Wl_hh[(size_t)k * 512 + gcb + 4];
    }
    float4 bias4a = *(const float4*)&bias[layer * 512 + gcb];
    float4 bias4b = *(const float4*)&bias[layer * 512 + gcb + 4];
    if (kg != 15) {   // bias added exactly once per col (at the reduction root lane)
        bias4a = make_float4(0.f, 0.f, 0.f, 0.f);
        bias4b = make_float4(0.f, 0.f, 0.f, 0.f);
    }

    // staging coords: 32 threads/row x 4 floats
    const int sr = tid >> 5;               // 0..15
    const int sk = (tid & 31) << 2;        // 0,4,...,124
    const int skc = SKG(sk);

    // cell-update coords: 1 cell/thread
    const int ur = tid >> 5, uc = tid & 31;
    float creg = 0.f;

    __syncthreads();   // sAin zero-fill visible

    for (int t = 0; t < Tt; ++t) {
        const int s = t + layer;
        const int prev = (s - 1) & 3, cur = s & 3;   // depth-4 buffering
        const u32 expseq = (u32)(s - 1);

        // ---- anti-dep (depth-4 slack: target s-3; flags init -1 auto-pass early) ----
        if (adflag != nullptr) {
            const int target = s - 3;
            while (__hip_atomic_load(adflag, __ATOMIC_RELAXED, __HIP_MEMORY_SCOPE_AGENT) < target)
                ;
        }

        // ---- stage A tiles into LDS; the seq tags ARE the ready-signal ----
        if (layer == 0) {
            if (tid < 128) {
                int r = tid >> 3, i = tid & 7;
                sAin[r][i] = x[((size_t)(r0 + r) * Tt + t) * 8 + i];
            }
        } else {
            const u64* src = hbuf + ((size_t)prev * 3 + (layer - 1)) * Bsz * Hh
                           + (size_t)(r0 + sr) * Hh + sk;
            *(float4*)&sAin[sr][skc] = stage4(src, expseq);
        }
        if (t > 0) {
            const u64* src = hbuf + ((size_t)prev * 3 + layer) * Bsz * Hh
                           + (size_t)(r0 + sr) * Hh + sk;
            *(float4*)&sArec[sr][skc] = stage4(src, expseq);
        }
        __syncthreads();   // barA: staging done (also orders anti-dep poll before stores)

        // publish "staged slot s" (earliest legal point: my reads of s-1 are complete)
        if (tid == 0)
            __hip_atomic_store(myflag, s, __ATOMIC_RELAXED, __HIP_MEMORY_SCOPE_AGENT);

        // ---- GEMM: register weights x LDS A-slices (8 rows x 8 cols / thread) ----
#pragma unroll
        for (int j = 0; j < 8; j++) {
            const int r = rg * 8 + j;
            float4 acc0 = bias4a, acc1 = bias4b;
            {
                float4 a0 = *(const float4*)&sAin[r][ka];
                float4 a1 = *(const float4*)&sAin[r][ka + 4];
                FMA4(acc0, a0.x, wihA[0]); FMA4(acc1, a0.x, wihB[0]);
                FMA4(acc0, a0.y, wihA[1]); FMA4(acc1, a0.y, wihB[1]);
                FMA4(acc0, a0.z, wihA[2]); FMA4(acc1, a0.z, wihB[2]);
                FMA4(acc0, a0.w, wihA[3]); FMA4(acc1, a0.w, wihB[3]);
                FMA4(acc0, a1.x, wihA[4]); FMA4(acc1, a1.x, wihB[4]);
                FMA4(acc0, a1.y, wihA[5]); FMA4(acc1, a1.y, wihB[5]);
                FMA4(acc0, a1.z, wihA[6]); FMA4(acc1, a1.z, wihB[6]);
                FMA4(acc0, a1.w, wihA[7]); FMA4(acc1, a1.w, wihB[7]);
            }
            if (t > 0) {
                float4 b0 = *(const float4*)&sArec[r][ka];
                float4 b1 = *(const float4*)&sArec[r][ka + 4];
                FMA4(acc0, b0.x, whhA[0]); FMA4(acc1, b0.x, whhB[0]);
                FMA4(acc0, b0.y, whhA[1]); FMA4(acc1, b0.y, whhB[1]);
                FMA4(acc0, b0.z, whhA[2]); FMA4(acc1, b0.z, whhB[2]);
                FMA4(acc0, b0.w, whhA[3]); FMA4(acc1, b0.w, whhB[3]);
                FMA4(acc0, b1.x, whhA[4]); FMA4(acc1, b1.x, whhB[4]);
                FMA4(acc0, b1.y, whhA[5]); FMA4(acc1, b1.y, whhB[5]);
                FMA4(acc0, b1.z, whhA[6]); FMA4(acc1, b1.z, whhB[6]);
                FMA4(acc0, b1.w, whhA[7]); FMA4(acc1, b1.w, whhB[7]);
            }
            acc0 = red16(acc0);            // lane kg==15: full sum + bias
            acc1 = red16(acc1);
            if (kg == 15) {
                *(float4*)&sG[r][cbase]     = acc0;
                *(float4*)&sG[r][cbase + 4] = acc1;
            }
        }
        __syncthreads();   // barB: sG visible

        // ---- LSTM cell update: 1 cell/thread; store (h,seq) -- the signal itself ----
        {
            float gi = sG[ur][uc],      gf = sG[ur][32 + uc];
            float gg = sG[ur][64 + uc], go = sG[ur][96 + uc];
            float si = 1.f / (1.f + __expf(-gi));
            float sf = 1.f / (1.f + __expf(-gf));
            float so = 1.f / (1.f + __expf(-go));
            creg = sf * creg + si * tanhf(gg);
            u64* dst = hbuf + ((size_t)cur * 3 + layer) * Bsz * Hh
                     + (size_t)(r0 + ur) * Hh + hc0 + uc;
            st_h_agent(dst, so * tanhf(creg), (u32)s);
        }
        // no barrier: next-slot staging conflicts only with GEMM reads (ended at barB)
        // and cell's sG reads (ordered before next GEMM by next barA).
    }
}

__global__ void fc_kernel(const float* __restrict__ ws, const float* __restrict__ Wfc,
                          const float* __restrict__ bfc, float* __restrict__ out)
{
    // final h of layer2 written at s=513 -> 513&3 = 1 -> hbuf[1][2]
    const u64* h2 = (const u64*)(ws + OFF_HBUF) + (size_t)(1 * 3 + 2) * Bsz * Hh;
    int b = threadIdx.x;   // 256 threads
    float a0 = bfc[0], a1 = bfc[1], a2 = bfc[2];
    for (int k = 0; k < 128; k++) {
        float h = __uint_as_float((u32)h2[b * 128 + k]);
        a0 += h * Wfc[0 * 128 + k];
        a1 += h * Wfc[1 * 128 + k];
        a2 += h * Wfc[2 * 128 + k];
    }
    out[b * 3 + 0] = a0;
    out[b * 3 + 1] = a1;
    out[b * 3 + 2] = a2;
}

extern "C" void kernel_launch(void* const* d_in, const int* in_sizes, int n_in,
                              void* d_out, int out_size, void* d_ws, size_t ws_size,
                              hipStream_t stream)
{
    const float* x = (const float*)d_in[0];
    float* ws = (float*)d_ws;

    prep_kernel<<<24, 256, 0, stream>>>(
        (const float*)d_in[1],  (const float*)d_in[2],  (const float*)d_in[3],  (const float*)d_in[4],
        (const float*)d_in[5],  (const float*)d_in[6],  (const float*)d_in[7],  (const float*)d_in[8],
        (const float*)d_in[9],  (const float*)d_in[10], (const float*)d_in[11], (const float*)d_in[12],
        ws);

    // cooperative launch solely for the co-residency guarantee (no grid.sync inside)
    void* args[2] = { (void*)&x, (void*)&ws };
    hipLaunchCooperativeKernel((void*)lstm_kernel, dim3(192), dim3(512), args, 0, stream);

    fc_kernel<<<1, 256, 0, stream>>>(ws, (const float*)d_in[13], (const float*)d_in[14], (float*)d_out);
}